// Round 1
// baseline (72.054 us; speedup 1.0000x reference)
//
#include <hip/hip_runtime.h>

// 11-layer MLP, widths 8->6->6->6->6->6->6->4->4->4->4->1, sigmoid after
// every layer. One thread per row; weights are wave-uniform (scalar-cache
// loads); sigmoid via hardware exp2 + rcp.

__device__ __forceinline__ float fast_sigmoid(float x) {
    // sigmoid(x) = 1 / (1 + exp(-x)) = 1 / (1 + 2^(-x*log2(e)))
    float e = __builtin_amdgcn_exp2f(-x * 1.44269504088896340736f);
    return __builtin_amdgcn_rcpf(1.0f + e);
}

template <int FI, int FO>
__device__ __forceinline__ void layer(const float* h, float* o,
                                      const float* __restrict__ W,
                                      const float* __restrict__ b) {
#pragma unroll
    for (int j = 0; j < FO; ++j) {
        float acc = b[j];
#pragma unroll
        for (int i = 0; i < FI; ++i) {
            acc = fmaf(h[i], W[j * FI + i], acc);  // W[j][i]: out = h @ W^T + b
        }
        o[j] = fast_sigmoid(acc);
    }
}

__global__ __launch_bounds__(256) void mlp11_kernel(
    const float* __restrict__ x,
    const float* __restrict__ W1,  const float* __restrict__ b1,
    const float* __restrict__ W2,  const float* __restrict__ b2,
    const float* __restrict__ W3,  const float* __restrict__ b3,
    const float* __restrict__ W4,  const float* __restrict__ b4,
    const float* __restrict__ W5,  const float* __restrict__ b5,
    const float* __restrict__ W6,  const float* __restrict__ b6,
    const float* __restrict__ W7,  const float* __restrict__ b7,
    const float* __restrict__ W8,  const float* __restrict__ b8,
    const float* __restrict__ W9,  const float* __restrict__ b9,
    const float* __restrict__ W10, const float* __restrict__ b10,
    const float* __restrict__ W11, const float* __restrict__ b11,
    float* __restrict__ out, int nrows) {
    int row = blockIdx.x * 256 + (int)threadIdx.x;
    if (row >= nrows) return;

    const float4* xv = reinterpret_cast<const float4*>(x) + (size_t)row * 2;
    float4 a = xv[0];
    float4 c = xv[1];

    float h0[8] = {a.x, a.y, a.z, a.w, c.x, c.y, c.z, c.w};
    float h1[8];

    layer<8, 6>(h0, h1, W1, b1);
    layer<6, 6>(h1, h0, W2, b2);
    layer<6, 6>(h0, h1, W3, b3);
    layer<6, 6>(h1, h0, W4, b4);
    layer<6, 6>(h0, h1, W5, b5);
    layer<6, 6>(h1, h0, W6, b6);
    layer<6, 4>(h0, h1, W7, b7);
    layer<4, 4>(h1, h0, W8, b8);
    layer<4, 4>(h0, h1, W9, b9);
    layer<4, 4>(h1, h0, W10, b10);
    layer<4, 1>(h0, h1, W11, b11);

    out[row] = h1[0];
}

extern "C" void kernel_launch(void* const* d_in, const int* in_sizes, int n_in,
                              void* d_out, int out_size, void* d_ws, size_t ws_size,
                              hipStream_t stream) {
    const float* x = (const float*)d_in[0];
    const float* W[11];
    const float* b[11];
    for (int i = 0; i < 11; ++i) {
        W[i] = (const float*)d_in[1 + 2 * i];
        b[i] = (const float*)d_in[2 + 2 * i];
    }
    float* out = (float*)d_out;
    int nrows = in_sizes[0] / 8;

    int blocks = (nrows + 255) / 256;
    mlp11_kernel<<<blocks, 256, 0, stream>>>(
        x,
        W[0], b[0], W[1], b[1], W[2], b[2], W[3], b[3], W[4], b[4],
        W[5], b[5], W[6], b[6], W[7], b[7], W[8], b[8], W[9], b[9],
        W[10], b[10],
        out, nrows);
}